// Round 1
// baseline (401.786 us; speedup 1.0000x reference)
//
#include <hip/hip_runtime.h>
#include <stdint.h>

typedef unsigned short u16;
typedef __attribute__((ext_vector_type(4))) float f32x4;
typedef __attribute__((ext_vector_type(8))) short bf16x8;
typedef __attribute__((ext_vector_type(8))) u16 u16x8;

#define T_SEQ  2048
#define EMB    2048
#define HD     128
#define NHEAD  16
#define NTOK   4096
#define NE3    6144
#define SCALE  0.29730177875068026f   // 128^-0.25
#define LOG2E  1.44269504088896f

typedef __attribute__((address_space(3))) char* lds_t;
typedef const __attribute__((address_space(1))) char* gl_t;

__device__ __forceinline__ void gld16(const void* g, void* l) {
  __builtin_amdgcn_global_load_lds((gl_t)g, (lds_t)l, 16, 0, 0);
}

__device__ __forceinline__ u16 f2bf(float f) {
  union { float f; uint32_t u; } c; c.f = f;
  uint32_t r = c.u + 0x7fffu + ((c.u >> 16) & 1u);
  return (u16)(r >> 16);
}

// ---------------- fp32 -> bf16 conversion (memory-bound) ----------------
__global__ __launch_bounds__(256) void cvt_bf16(const float* __restrict__ in,
                                                u16* __restrict__ out, int n8) {
  int i = blockIdx.x * 256 + threadIdx.x;
  if (i >= n8) return;
  const float4* p = (const float4*)in + (size_t)i * 2;
  float4 a = p[0], b = p[1];
  u16x8 o;
  o[0]=f2bf(a.x); o[1]=f2bf(a.y); o[2]=f2bf(a.z); o[3]=f2bf(a.w);
  o[4]=f2bf(b.x); o[5]=f2bf(b.y); o[6]=f2bf(b.z); o[7]=f2bf(b.w);
  *((u16x8*)out + i) = o;
}

// ---------------- m97-style 128x128 bf16 GEMM, B^T layout ----------------
// C[m][n] = sum_k A[m][k] * Bm[n][k]
// EPI==0: write fp32 C (output projection, no bias per reference)
// EPI==1: QKV epilogue: +bias, RoPE on K/Q segments (angle row = n % T),
//         scale by D^-0.25, scatter to Qh/Kh [bh][t][d] and Vt [bh][d][t] (bf16)
template<int EPI>
__global__ __launch_bounds__(256, 2) void gemm_bt(
    const u16* __restrict__ A, const u16* __restrict__ Bm, int K, int N,
    const float* __restrict__ cosT, const float* __restrict__ sinT,
    const float* __restrict__ bias,
    u16* __restrict__ Qh, u16* __restrict__ Kh, u16* __restrict__ Vt,
    float* __restrict__ Cout)
{
  __shared__ u16 As[128*32];
  __shared__ u16 Bs[128*32];
  const int tid = threadIdx.x;
  const int lane = tid & 63, w = tid >> 6;
  const int wm = w >> 1, wn = w & 1;
  const int l15 = lane & 15, lq = lane >> 4;
  const int bM = blockIdx.x, bN = blockIdx.y;

  const u16* Ab = A + (size_t)bM * 128 * K;
  const u16* Bb = Bm + (size_t)bN * 128 * K;
  const int r0 = tid >> 2;              // row covered by this lane's 16B
  const int c0 = (tid & 3) * 8;         // ushort offset within 32-elem row

  f32x4 acc[4][4] = {};

  for (int kt = 0; kt < K; kt += 32) {
    gld16(Ab + (size_t)r0        * K + kt + c0, (char*)As + tid*16);
    gld16(Ab + (size_t)(r0 + 64) * K + kt + c0, (char*)As + tid*16 + 4096);
    gld16(Bb + (size_t)r0        * K + kt + c0, (char*)Bs + tid*16);
    gld16(Bb + (size_t)(r0 + 64) * K + kt + c0, (char*)Bs + tid*16 + 4096);
    __syncthreads();
    bf16x8 af[4], bfr[4];
    #pragma unroll
    for (int i = 0; i < 4; i++)
      af[i] = *(const bf16x8*)(As + (wm*64 + i*16 + l15)*32 + lq*8);
    #pragma unroll
    for (int i = 0; i < 4; i++)
      bfr[i] = *(const bf16x8*)(Bs + (wn*64 + i*16 + l15)*32 + lq*8);
    #pragma unroll
    for (int mi = 0; mi < 4; mi++)
      #pragma unroll
      for (int ni = 0; ni < 4; ni++)
        acc[mi][ni] = __builtin_amdgcn_mfma_f32_16x16x32_bf16(af[mi], bfr[ni], acc[mi][ni], 0, 0, 0);
    __syncthreads();
  }

  if (EPI == 0) {
    #pragma unroll
    for (int mi = 0; mi < 4; mi++) {
      int row = bM*128 + wm*64 + mi*16 + lq*4;
      #pragma unroll
      for (int ni = 0; ni < 4; ni++) {
        int col = bN*128 + wn*64 + ni*16 + l15;
        #pragma unroll
        for (int r = 0; r < 4; r++)
          Cout[(size_t)(row + r) * N + col] = acc[mi][ni][r];
      }
    }
  } else {
    // block-uniform segment (0=K,1=V,2=Q) and head: BN=128 aligns with both
    const int cbase = bN*128 + wn*64;
    const int seg  = cbase >> 11;
    const int head = (cbase >> 7) & 15;
    #pragma unroll
    for (int mi = 0; mi < 4; mi++) {
      #pragma unroll
      for (int ni = 0; ni < 4; ni++) {
        int col = cbase + ni*16 + l15;
        int d = col & 127;
        float bi = bias[col];
        f32x4 v = acc[mi][ni];
        #pragma unroll
        for (int r = 0; r < 4; r++) {
          int n = bM*128 + wm*64 + mi*16 + lq*4 + r;   // flat token = t*B + b
          float val = v[r] + bi;
          int t = n >> 1, b = n & 1;
          int bh = b*NHEAD + head;
          if (seg == 1) {
            Vt[((size_t)bh*HD + d)*T_SEQ + t] = f2bf(val);
          } else {
            // RoPE: reference's flat reshape makes angle row = n % T
            float par = __shfl_xor(val, 1);            // partner of (even,odd) pair
            int fidx = d >> 1;
            float cs = cosT[(n & (T_SEQ-1))*64 + fidx];
            float sn = sinT[(n & (T_SEQ-1))*64 + fidx];
            val = (d & 1) ? (par*sn + val*cs) : (val*cs - par*sn);
            val *= SCALE;
            u16* dst = (seg == 0) ? Kh : Qh;
            dst[((size_t)bh*T_SEQ + t)*HD + d] = f2bf(val);
          }
        }
      }
    }
  }
}

// ---------------- causal flash attention, bf16 MFMA ----------------
// grid: (qb=32, bh=32). 4 waves, each owns 16 q rows; KB=64 keys per tile.
// K tile [64][128] and Vt tile [128][64] staged via global_load_lds with
// XOR swizzle (byte ^= (row&7)<<4) -> conflict-free ds_read_b128.
__global__ __launch_bounds__(256, 2) void attn_fwd(
    const u16* __restrict__ Qh, const u16* __restrict__ Kh,
    const u16* __restrict__ Vt, u16* __restrict__ O)
{
  const int qb = blockIdx.x, bh = blockIdx.y;
  const int tid = threadIdx.x, lane = tid & 63, w = tid >> 6;
  const int l15 = lane & 15, lq = lane >> 4;

  __shared__ u16 Ks[64*128];     // 16KB, swizzled
  __shared__ u16 Vs[128*64];     // 16KB, swizzled
  __shared__ u16 Ps[4][16][72];  // per-wave P tile, padded rows (2-way free)

  const int q0 = qb*64 + w*16;
  bf16x8 qf[4];
  #pragma unroll
  for (int dc = 0; dc < 4; dc++)
    qf[dc] = *(const bf16x8*)(Qh + ((size_t)bh*T_SEQ + q0 + l15)*HD + dc*32 + lq*8);

  f32x4 o[8] = {};
  float m[4], l_[4];
  #pragma unroll
  for (int r = 0; r < 4; r++) { m[r] = -1e30f; l_[r] = 0.f; }

  const int nkb = qb + 1;
  for (int kb = 0; kb < nkb; ++kb) {
    // stage K tile (rows 256B) and Vt tile (rows 128B), swizzled source
    #pragma unroll
    for (int j = 0; j < 4; j++) {
      int lb = tid*16 + j*4096;
      int row = lb >> 8, bir = lb & 255;
      int sb = bir ^ ((row & 7) << 4);
      gld16((const char*)Kh + (((size_t)bh*T_SEQ + kb*64 + row) << 8) + sb,
            (char*)Ks + lb);
    }
    #pragma unroll
    for (int j = 0; j < 4; j++) {
      int lb = tid*16 + j*4096;
      int row = lb >> 7, bir = lb & 127;
      int sb = bir ^ ((row & 7) << 4);
      gld16((const char*)Vt + ((size_t)(bh*HD + row)*T_SEQ)*2 + kb*128 + sb,
            (char*)Vs + lb);
    }
    __syncthreads();

    // S = Q K^T  (16 q x 64 keys per wave)
    f32x4 sacc[4];
    #pragma unroll
    for (int nf = 0; nf < 4; nf++) {
      f32x4 z = {};
      sacc[nf] = z;
      #pragma unroll
      for (int dc = 0; dc < 4; dc++) {
        int row = nf*16 + l15;
        int bir = (dc*64 + lq*16) ^ ((row & 7) << 4);
        bf16x8 kf = *(const bf16x8*)((const char*)Ks + row*256 + bir);
        sacc[nf] = __builtin_amdgcn_mfma_f32_16x16x32_bf16(qf[dc], kf, sacc[nf], 0, 0, 0);
      }
    }

    if (kb == qb) {   // diagonal block: causal mask
      #pragma unroll
      for (int nf = 0; nf < 4; nf++)
        #pragma unroll
        for (int r = 0; r < 4; r++) {
          int key = kb*64 + nf*16 + l15;
          int qr  = q0 + lq*4 + r;
          if (key > qr) sacc[nf][r] = -1e30f;
        }
    }

    // online softmax (rows live in lanes of same quarter; reduce over 16 lanes)
    #pragma unroll
    for (int r = 0; r < 4; r++) {
      float mx = fmaxf(fmaxf(sacc[0][r], sacc[1][r]), fmaxf(sacc[2][r], sacc[3][r]));
      mx = fmaxf(mx, __shfl_xor(mx, 1));
      mx = fmaxf(mx, __shfl_xor(mx, 2));
      mx = fmaxf(mx, __shfl_xor(mx, 4));
      mx = fmaxf(mx, __shfl_xor(mx, 8));
      float newm = fmaxf(m[r], mx);
      float scale = exp2f((m[r] - newm) * LOG2E);
      float sum = 0.f;
      #pragma unroll
      for (int nf = 0; nf < 4; nf++) {
        float p = exp2f((sacc[nf][r] - newm) * LOG2E);
        sacc[nf][r] = p;
        sum += p;
      }
      sum += __shfl_xor(sum, 1);
      sum += __shfl_xor(sum, 2);
      sum += __shfl_xor(sum, 4);
      sum += __shfl_xor(sum, 8);
      l_[r] = l_[r] * scale + sum;
      m[r] = newm;
      #pragma unroll
      for (int nf = 0; nf < 8; nf++) o[nf][r] *= scale;
    }

    // P -> bf16 tile in LDS (wave-private; compiler inserts lgkmcnt)
    #pragma unroll
    for (int nf = 0; nf < 4; nf++)
      #pragma unroll
      for (int r = 0; r < 4; r++)
        Ps[w][lq*4 + r][nf*16 + l15] = f2bf(sacc[nf][r]);

    // O += P V   (A-frag from Ps, B-frag from swizzled Vs)
    #pragma unroll
    for (int kc = 0; kc < 2; kc++) {
      bf16x8 pf = *(const bf16x8*)(&Ps[w][l15][kc*32 + lq*8]);
      #pragma unroll
      for (int nf = 0; nf < 8; nf++) {
        int row = nf*16 + l15;
        int bir = (kc*64 + lq*16) ^ ((row & 7) << 4);
        bf16x8 vf = *(const bf16x8*)((const char*)Vs + row*128 + bir);
        o[nf] = __builtin_amdgcn_mfma_f32_16x16x32_bf16(pf, vf, o[nf], 0, 0, 0);
      }
    }
    __syncthreads();   // before next tile overwrites Ks/Vs
  }

  // epilogue: O row -> [t*B+b][h*D+d] bf16 for the output GEMM
  const int b = bh >> 4, h = bh & 15;
  #pragma unroll
  for (int r = 0; r < 4; r++) {
    float inv = 1.0f / l_[r];
    int t = q0 + lq*4 + r;
    size_t base = ((size_t)(t*2 + b))*EMB + h*HD;
    #pragma unroll
    for (int nf = 0; nf < 8; nf++)
      O[base + nf*16 + l15] = f2bf(o[nf][r] * inv);
  }
}

// ---------------- launch ----------------
extern "C" void kernel_launch(void* const* d_in, const int* in_sizes, int n_in,
                              void* d_out, int out_size, void* d_ws, size_t ws_size,
                              hipStream_t stream) {
  const float* query = (const float*)d_in[0];
  const float* Wqkv  = (const float*)d_in[1];
  const float* bqkv  = (const float*)d_in[2];
  const float* Wo    = (const float*)d_in[3];
  // d_in[4] = bo — reference does NOT add it
  const float* fcos  = (const float*)d_in[5];
  const float* fsin  = (const float*)d_in[6];
  float* out = (float*)d_out;
  char* ws = (char*)d_ws;

  // workspace layout (bytes), total 96MB
  u16* WQb = (u16*)(ws + 0);          // 6144x2048 bf16 = 25165824
  u16* WOb = (u16*)(ws + 25165824);   // 2048x2048 bf16 =  8388608
  u16* A1  = (u16*)(ws + 33554432);   // 4096x2048 bf16 = 16777216 (query; reused as attn out)
  u16* QH  = (u16*)(ws + 50331648);   // [32][2048][128] bf16
  u16* KH  = (u16*)(ws + 67108864);
  u16* VT  = (u16*)(ws + 83886080);   // [32][128][2048] bf16  (end: 100663296)

  cvt_bf16<<<4096, 256, 0, stream>>>(query, A1, 1048576);
  cvt_bf16<<<6144, 256, 0, stream>>>(Wqkv, WQb, 1572864);
  cvt_bf16<<<2048, 256, 0, stream>>>(Wo,   WOb,  524288);

  gemm_bt<1><<<dim3(32, 48), 256, 0, stream>>>(A1, WQb, 2048, NE3,
                                               fcos, fsin, bqkv, QH, KH, VT, nullptr);

  attn_fwd<<<dim3(32, 32), 256, 0, stream>>>(QH, KH, VT, A1);

  gemm_bt<0><<<dim3(32, 16), 256, 0, stream>>>(A1, WOb, 2048, EMB,
                                               nullptr, nullptr, nullptr,
                                               nullptr, nullptr, nullptr, out);
}

// Round 2
// 360.745 us; speedup vs baseline: 1.1138x; 1.1138x over previous
//
#include <hip/hip_runtime.h>
#include <stdint.h>

typedef unsigned short u16;
typedef __attribute__((ext_vector_type(4))) float f32x4;
typedef __attribute__((ext_vector_type(8))) short bf16x8;
typedef __attribute__((ext_vector_type(8))) u16 u16x8;

#define T_SEQ  2048
#define EMB    2048
#define HD     128
#define NHEAD  16
#define NTOK   4096
#define NE3    6144
#define SCALE  0.29730177875068026f   // 128^-0.25
#define LOG2E  1.44269504088896f

typedef __attribute__((address_space(3))) char* lds_t;
typedef const __attribute__((address_space(1))) char* gl_t;

__device__ __forceinline__ void gld16(const void* g, void* l) {
  __builtin_amdgcn_global_load_lds((gl_t)g, (lds_t)l, 16, 0, 0);
}

__device__ __forceinline__ u16 f2bf(float f) {
  union { float f; uint32_t u; } c; c.f = f;
  uint32_t r = c.u + 0x7fffu + ((c.u >> 16) & 1u);
  return (u16)(r >> 16);
}

// ---------------- fp32 -> bf16 conversion (memory-bound) ----------------
__global__ __launch_bounds__(256) void cvt_bf16(const float* __restrict__ in,
                                                u16* __restrict__ out, int n8) {
  int i = blockIdx.x * 256 + threadIdx.x;
  if (i >= n8) return;
  const float4* p = (const float4*)in + (size_t)i * 2;
  float4 a = p[0], b = p[1];
  u16x8 o;
  o[0]=f2bf(a.x); o[1]=f2bf(a.y); o[2]=f2bf(a.z); o[3]=f2bf(a.w);
  o[4]=f2bf(b.x); o[5]=f2bf(b.y); o[6]=f2bf(b.z); o[7]=f2bf(b.w);
  *((u16x8*)out + i) = o;
}

// ---------------- m97-style 128x128 bf16 GEMM, B^T layout ----------------
// C[m][n] = sum_k A[m][k] * Bm[n][k]
// EPI==0: write fp32 C (output projection, no bias per reference)
// EPI==1: QKV epilogue: +bias, RoPE on K/Q segments (angle row = n % T),
//         scale by D^-0.25, scatter to Qh/Kh [bh][t][d] and Vt [bh][d][t] (bf16)
template<int EPI>
__global__ __launch_bounds__(256, 2) void gemm_bt(
    const u16* __restrict__ A, const u16* __restrict__ Bm, int K, int N,
    const float* __restrict__ cosT, const float* __restrict__ sinT,
    const float* __restrict__ bias,
    u16* __restrict__ Qh, u16* __restrict__ Kh, u16* __restrict__ Vt,
    float* __restrict__ Cout)
{
  __shared__ u16 As[128*32];
  __shared__ u16 Bs[128*32];
  const int tid = threadIdx.x;
  const int lane = tid & 63, w = tid >> 6;
  const int wm = w >> 1, wn = w & 1;
  const int l15 = lane & 15, lq = lane >> 4;
  const int bM = blockIdx.x, bN = blockIdx.y;

  const u16* Ab = A + (size_t)bM * 128 * K;
  const u16* Bb = Bm + (size_t)bN * 128 * K;
  const int r0 = tid >> 2;              // row covered by this lane's 16B
  const int c0 = (tid & 3) * 8;         // ushort offset within 32-elem row

  f32x4 acc[4][4] = {};

  for (int kt = 0; kt < K; kt += 32) {
    gld16(Ab + (size_t)r0        * K + kt + c0, (char*)As + tid*16);
    gld16(Ab + (size_t)(r0 + 64) * K + kt + c0, (char*)As + tid*16 + 4096);
    gld16(Bb + (size_t)r0        * K + kt + c0, (char*)Bs + tid*16);
    gld16(Bb + (size_t)(r0 + 64) * K + kt + c0, (char*)Bs + tid*16 + 4096);
    __syncthreads();
    bf16x8 af[4], bfr[4];
    #pragma unroll
    for (int i = 0; i < 4; i++)
      af[i] = *(const bf16x8*)(As + (wm*64 + i*16 + l15)*32 + lq*8);
    #pragma unroll
    for (int i = 0; i < 4; i++)
      bfr[i] = *(const bf16x8*)(Bs + (wn*64 + i*16 + l15)*32 + lq*8);
    #pragma unroll
    for (int mi = 0; mi < 4; mi++)
      #pragma unroll
      for (int ni = 0; ni < 4; ni++)
        acc[mi][ni] = __builtin_amdgcn_mfma_f32_16x16x32_bf16(af[mi], bfr[ni], acc[mi][ni], 0, 0, 0);
    __syncthreads();
  }

  if (EPI == 0) {
    #pragma unroll
    for (int mi = 0; mi < 4; mi++) {
      int row = bM*128 + wm*64 + mi*16 + lq*4;
      #pragma unroll
      for (int ni = 0; ni < 4; ni++) {
        int col = bN*128 + wn*64 + ni*16 + l15;
        #pragma unroll
        for (int r = 0; r < 4; r++)
          Cout[(size_t)(row + r) * N + col] = acc[mi][ni][r];
      }
    }
  } else {
    // block-uniform segment (0=K,1=V,2=Q) and head: BN=128 aligns with both
    const int cbase = bN*128 + wn*64;
    const int seg  = cbase >> 11;
    const int head = (cbase >> 7) & 15;
    #pragma unroll
    for (int mi = 0; mi < 4; mi++) {
      #pragma unroll
      for (int ni = 0; ni < 4; ni++) {
        int col = cbase + ni*16 + l15;
        int d = col & 127;
        float bi = bias[col];
        f32x4 v = acc[mi][ni];
        #pragma unroll
        for (int r = 0; r < 4; r++) {
          int n = bM*128 + wm*64 + mi*16 + lq*4 + r;   // flat token = t*B + b
          float val = v[r] + bi;
          int t = n >> 1, b = n & 1;
          int bh = b*NHEAD + head;
          if (seg == 1) {
            Vt[((size_t)bh*HD + d)*T_SEQ + t] = f2bf(val);
          } else {
            // RoPE: reference's flat reshape makes angle row = n % T
            float par = __shfl_xor(val, 1);            // partner of (even,odd) pair
            int fidx = d >> 1;
            float cs = cosT[(n & (T_SEQ-1))*64 + fidx];
            float sn = sinT[(n & (T_SEQ-1))*64 + fidx];
            val = (d & 1) ? (par*sn + val*cs) : (val*cs - par*sn);
            val *= SCALE;
            u16* dst = (seg == 0) ? Kh : Qh;
            dst[((size_t)bh*T_SEQ + t)*HD + d] = f2bf(val);
          }
        }
      }
    }
  }
}

// ---------------- causal flash attention, bf16 MFMA ----------------
// 1D grid of 1024 blocks, work-balanced remap: each CU-residue class
// {c, c+256, c+512, c+768} gets qb multiset {b, 31-b, b, 31-b} = 66 tiles.
// LDS exactly 40960B -> 4 blocks/CU, whole grid co-resident, no tail.
__global__ __launch_bounds__(256, 4) void attn_fwd(
    const u16* __restrict__ Qh, const u16* __restrict__ Kh,
    const u16* __restrict__ Vt, u16* __restrict__ O)
{
  const int i = blockIdx.x;
  const int kk = i >> 8, c = i & 255;
  const int bh = (c >> 5) + kk * 8;
  const int b5 = c & 31;
  const int qb = (kk & 1) ? (31 - b5) : b5;

  const int tid = threadIdx.x, lane = tid & 63, w = tid >> 6;
  const int l15 = lane & 15, lq = lane >> 4;

  __shared__ u16 Ks[64*128];      // 16384B, swizzled
  __shared__ u16 Vs[128*64];      // 16384B, swizzled
  __shared__ char Ps[4][2048];    // 8192B: per-wave 16 rows x 128B, XOR-swizzled

  const int q0 = qb*64 + w*16;
  bf16x8 qf[4];
  #pragma unroll
  for (int dc = 0; dc < 4; dc++)
    qf[dc] = *(const bf16x8*)(Qh + ((size_t)bh*T_SEQ + q0 + l15)*HD + dc*32 + lq*8);

  f32x4 o[8] = {};
  float m[4], l_[4];
  #pragma unroll
  for (int r = 0; r < 4; r++) { m[r] = -1e30f; l_[r] = 0.f; }

  const int nkb = qb + 1;
  for (int kb = 0; kb < nkb; ++kb) {
    // stage K tile (rows 256B) and Vt tile (rows 128B), swizzled source
    #pragma unroll
    for (int j = 0; j < 4; j++) {
      int lb = tid*16 + j*4096;
      int row = lb >> 8, bir = lb & 255;
      int sb = bir ^ ((row & 7) << 4);
      gld16((const char*)Kh + (((size_t)bh*T_SEQ + kb*64 + row) << 8) + sb,
            (char*)Ks + lb);
    }
    #pragma unroll
    for (int j = 0; j < 4; j++) {
      int lb = tid*16 + j*4096;
      int row = lb >> 7, bir = lb & 127;
      int sb = bir ^ ((row & 7) << 4);
      gld16((const char*)Vt + ((size_t)(bh*HD + row)*T_SEQ)*2 + kb*128 + sb,
            (char*)Vs + lb);
    }
    __syncthreads();

    // S = Q K^T  (16 q x 64 keys per wave)
    f32x4 sacc[4];
    #pragma unroll
    for (int nf = 0; nf < 4; nf++) {
      f32x4 z = {};
      sacc[nf] = z;
      #pragma unroll
      for (int dc = 0; dc < 4; dc++) {
        int row = nf*16 + l15;
        int bir = (dc*64 + lq*16) ^ ((row & 7) << 4);
        bf16x8 kf = *(const bf16x8*)((const char*)Ks + row*256 + bir);
        sacc[nf] = __builtin_amdgcn_mfma_f32_16x16x32_bf16(qf[dc], kf, sacc[nf], 0, 0, 0);
      }
    }

    if (kb == qb) {   // diagonal block: causal mask
      #pragma unroll
      for (int nf = 0; nf < 4; nf++)
        #pragma unroll
        for (int r = 0; r < 4; r++) {
          int key = kb*64 + nf*16 + l15;
          int qr  = q0 + lq*4 + r;
          if (key > qr) sacc[nf][r] = -1e30f;
        }
    }

    // online softmax (row q = q0+lq*4+r lives in 16 lanes of same lq)
    #pragma unroll
    for (int r = 0; r < 4; r++) {
      float mx = fmaxf(fmaxf(sacc[0][r], sacc[1][r]), fmaxf(sacc[2][r], sacc[3][r]));
      mx = fmaxf(mx, __shfl_xor(mx, 1));
      mx = fmaxf(mx, __shfl_xor(mx, 2));
      mx = fmaxf(mx, __shfl_xor(mx, 4));
      mx = fmaxf(mx, __shfl_xor(mx, 8));
      float newm = fmaxf(m[r], mx);
      float scale = exp2f((m[r] - newm) * LOG2E);
      float sum = 0.f;
      #pragma unroll
      for (int nf = 0; nf < 4; nf++) {
        float p = exp2f((sacc[nf][r] - newm) * LOG2E);
        sacc[nf][r] = p;
        sum += p;
      }
      sum += __shfl_xor(sum, 1);
      sum += __shfl_xor(sum, 2);
      sum += __shfl_xor(sum, 4);
      sum += __shfl_xor(sum, 8);
      l_[r] = l_[r] * scale + sum;
      m[r] = newm;
      #pragma unroll
      for (int nf = 0; nf < 8; nf++) o[nf][r] *= scale;
    }

    // P -> bf16 tile in wave-private LDS slab, XOR-swizzled rows (128B row)
    #pragma unroll
    for (int nf = 0; nf < 4; nf++)
      #pragma unroll
      for (int r = 0; r < 4; r++) {
        int prow = lq*4 + r;
        int pbyte = prow*128 + ((((nf*16 + l15)*2)) ^ ((prow & 7) << 4));
        *(u16*)(Ps[w] + pbyte) = f2bf(sacc[nf][r]);
      }

    // O += P V   (A-frag from Ps, B-frag from swizzled Vs)
    #pragma unroll
    for (int kc = 0; kc < 2; kc++) {
      int pb = (kc*64 + lq*16) ^ ((l15 & 7) << 4);
      bf16x8 pf = *(const bf16x8*)(Ps[w] + l15*128 + pb);
      #pragma unroll
      for (int nf = 0; nf < 8; nf++) {
        int row = nf*16 + l15;
        int bir = (kc*64 + lq*16) ^ ((row & 7) << 4);
        bf16x8 vf = *(const bf16x8*)((const char*)Vs + row*128 + bir);
        o[nf] = __builtin_amdgcn_mfma_f32_16x16x32_bf16(pf, vf, o[nf], 0, 0, 0);
      }
    }
    __syncthreads();   // before next tile overwrites Ks/Vs
  }

  // epilogue: O row -> [t*B+b][h*D+d] bf16 for the output GEMM
  const int b = bh >> 4, h = bh & 15;
  #pragma unroll
  for (int r = 0; r < 4; r++) {
    float inv = 1.0f / l_[r];
    int t = q0 + lq*4 + r;
    size_t base = ((size_t)(t*2 + b))*EMB + h*HD;
    #pragma unroll
    for (int nf = 0; nf < 8; nf++)
      O[base + nf*16 + l15] = f2bf(o[nf][r] * inv);
  }
}

// ---------------- launch ----------------
extern "C" void kernel_launch(void* const* d_in, const int* in_sizes, int n_in,
                              void* d_out, int out_size, void* d_ws, size_t ws_size,
                              hipStream_t stream) {
  const float* query = (const float*)d_in[0];
  const float* Wqkv  = (const float*)d_in[1];
  const float* bqkv  = (const float*)d_in[2];
  const float* Wo    = (const float*)d_in[3];
  // d_in[4] = bo — reference does NOT add it
  const float* fcos  = (const float*)d_in[5];
  const float* fsin  = (const float*)d_in[6];
  float* out = (float*)d_out;
  char* ws = (char*)d_ws;

  // workspace layout (bytes), total 96MB
  u16* WQb = (u16*)(ws + 0);          // 6144x2048 bf16 = 25165824
  u16* WOb = (u16*)(ws + 25165824);   // 2048x2048 bf16 =  8388608
  u16* A1  = (u16*)(ws + 33554432);   // 4096x2048 bf16 = 16777216 (query; reused as attn out)
  u16* QH  = (u16*)(ws + 50331648);   // [32][2048][128] bf16
  u16* KH  = (u16*)(ws + 67108864);
  u16* VT  = (u16*)(ws + 83886080);   // [32][128][2048] bf16  (end: 100663296)

  cvt_bf16<<<4096, 256, 0, stream>>>(query, A1, 1048576);
  cvt_bf16<<<6144, 256, 0, stream>>>(Wqkv, WQb, 1572864);
  cvt_bf16<<<2048, 256, 0, stream>>>(Wo,   WOb,  524288);

  gemm_bt<1><<<dim3(32, 48), 256, 0, stream>>>(A1, WQb, 2048, NE3,
                                               fcos, fsin, bqkv, QH, KH, VT, nullptr);

  attn_fwd<<<1024, 256, 0, stream>>>(QH, KH, VT, A1);

  gemm_bt<0><<<dim3(32, 16), 256, 0, stream>>>(A1, WOb, 2048, EMB,
                                               nullptr, nullptr, nullptr,
                                               nullptr, nullptr, nullptr, out);
}

// Round 4
// 359.400 us; speedup vs baseline: 1.1179x; 1.0037x over previous
//
#include <hip/hip_runtime.h>
#include <stdint.h>

typedef unsigned short u16;
typedef __attribute__((ext_vector_type(4))) float f32x4;
typedef __attribute__((ext_vector_type(8))) short bf16x8;
typedef __attribute__((ext_vector_type(8))) u16 u16x8;

#define T_SEQ  2048
#define EMB    2048
#define HD     128
#define NHEAD  16
#define NTOK   4096
#define NE3    6144
#define SCALE  0.29730177875068026f   // 128^-0.25
#define LOG2E  1.44269504088896f

typedef __attribute__((address_space(3))) char* lds_t;
typedef const __attribute__((address_space(1))) char* gl_t;

__device__ __forceinline__ void gld16(const void* g, void* l) {
  __builtin_amdgcn_global_load_lds((gl_t)g, (lds_t)l, 16, 0, 0);
}

__device__ __forceinline__ u16 f2bf(float f) {
  union { float f; uint32_t u; } c; c.f = f;
  uint32_t r = c.u + 0x7fffu + ((c.u >> 16) & 1u);
  return (u16)(r >> 16);
}

// gate: counted vmcnt + raw barrier + scheduling fence (never drains to 0)
#define GATE(N) do { \
  asm volatile("s_waitcnt vmcnt(" #N ")" ::: "memory"); \
  __builtin_amdgcn_s_barrier(); \
  __builtin_amdgcn_sched_barrier(0); \
} while (0)

// swizzled LDS fragment read: row-major [rows][64 bf16] (128B rows),
// byte ^= (row&7)<<4 -> per-16-lane group: 8 slots x 2 lanes = conflict-free
__device__ __forceinline__ bf16x8 ldsrd(const char* base, int row, int ks, int lq) {
  return *(const bf16x8*)(base + row*128 + ((ks*64 + lq*16) ^ ((row & 7) << 4)));
}

// stage one 8KB round (512 threads x 16B) linear-dest / inverse-swizzled-source
__device__ __forceinline__ void stage(const char* g, int rowstride, int ktb,
                                      char* l, int j, int tid) {
  int lb = j*8192 + tid*16;
  int row = lb >> 7;
  int src = (lb & 127) ^ ((row & 7) << 4);
  gld16(g + (size_t)row*rowstride + ktb + src, l + lb);
}

// ---------------- fp32 -> bf16 conversion (memory-bound) ----------------
__global__ __launch_bounds__(256) void cvt_bf16(const float* __restrict__ in,
                                                u16* __restrict__ out, int n8) {
  int i = blockIdx.x * 256 + threadIdx.x;
  if (i >= n8) return;
  const float4* p = (const float4*)in + (size_t)i * 2;
  float4 a = p[0], b = p[1];
  u16x8 o;
  o[0]=f2bf(a.x); o[1]=f2bf(a.y); o[2]=f2bf(a.z); o[3]=f2bf(a.w);
  o[4]=f2bf(b.x); o[5]=f2bf(b.y); o[6]=f2bf(b.z); o[7]=f2bf(b.w);
  *((u16x8*)out + i) = o;
}

// ---------------- 256x256 deep-pipelined bf16 GEMM, B^T layout ----------------
// C[m][n] = sum_k A[m][k] * Bm[n][k].  8 waves 2Mx4N, BK=64, LDS 128KB dbuf.
// Counted-vmcnt schedule (per K-tile): GATE(2); ph1(ks0,mh0: rd B0+B1+A, st B0,B1;
// 16 MFMA); ph2(ks1,mh0: st B2,B3); GATE(4); ph3(ks0,mh1: st A0,A2); ph4(ks1,mh1:
// st A1,A3).  Load order B0,B1,B2,B3,A0,A2,A1,A3 makes the ledger exact:
// in-flight = 8 at gate1 (wait first 6), 6 at gate2 (wait tile's A1,A3).
template<int EPI, int NBN>
__global__ __launch_bounds__(512, 2) void gemm8(
    const u16* __restrict__ A, const u16* __restrict__ Bm, int K, int N,
    const float* __restrict__ cosT, const float* __restrict__ sinT,
    const float* __restrict__ bias,
    u16* __restrict__ Qh, u16* __restrict__ Kh, u16* __restrict__ Vt,
    float* __restrict__ Cout)
{
  __shared__ __align__(16) char lds[131072];
  const int tid = threadIdx.x;
  const int lane = tid & 63, w = tid >> 6;
  const int wm = w >> 2, wn = w & 3;
  const int l15 = lane & 15, lq = lane >> 4;

  // bijective XCD swizzle (gridDim.x % 8 == 0 for both call sites)
  const int q8 = gridDim.x >> 3;
  const int swz = (blockIdx.x & 7) * q8 + (blockIdx.x >> 3);
  const int bM = swz / NBN, bN = swz % NBN;

  const char* Ag = (const char*)(A + (size_t)bM * 256 * K);
  const char* Bg = (const char*)(Bm + (size_t)bN * 256 * K);
  const int K2 = K * 2;
  const int nT = K >> 6;

  // prologue: stage tile 0 into buf0, canonical order
  stage(Bg, K2, 0, lds + 32768, 0, tid);
  stage(Bg, K2, 0, lds + 32768, 1, tid);
  stage(Bg, K2, 0, lds + 32768, 2, tid);
  stage(Bg, K2, 0, lds + 32768, 3, tid);
  stage(Ag, K2, 0, lds, 0, tid);
  stage(Ag, K2, 0, lds, 2, tid);
  stage(Ag, K2, 0, lds, 1, tid);
  stage(Ag, K2, 0, lds, 3, tid);

  f32x4 acc[8][4] = {};

  for (int t = 0; t < nT; ++t) {
    const char* Al = lds + (t & 1) * 65536;
    const char* Bl = Al + 32768;
    char* Asn = lds + ((t + 1) & 1) * 65536;
    char* Bsn = Asn + 32768;
    const int ktb = (t + 1 < nT ? t + 1 : t) << 7;   // tail: re-stage (unread)

    GATE(2);
    bf16x8 bf0[4], bf1[4], af[4];
    // ---- phase 1: ks0, mh0 ----
    #pragma unroll
    for (int ni = 0; ni < 4; ni++) bf0[ni] = ldsrd(Bl, wn*64 + ni*16 + l15, 0, lq);
    #pragma unroll
    for (int i = 0; i < 4; i++) af[i] = ldsrd(Al, wm*128 + i*16 + l15, 0, lq);
    stage(Bg, K2, ktb, Bsn, 0, tid);
    stage(Bg, K2, ktb, Bsn, 1, tid);
    __builtin_amdgcn_s_setprio(1);
    #pragma unroll
    for (int mi = 0; mi < 4; mi++)
      #pragma unroll
      for (int ni = 0; ni < 4; ni++)
        acc[mi][ni] = __builtin_amdgcn_mfma_f32_16x16x32_bf16(af[mi], bf0[ni], acc[mi][ni], 0, 0, 0);
    __builtin_amdgcn_s_setprio(0);
    // ---- phase 2: ks1, mh0 ----
    #pragma unroll
    for (int ni = 0; ni < 4; ni++) bf1[ni] = ldsrd(Bl, wn*64 + ni*16 + l15, 1, lq);
    #pragma unroll
    for (int i = 0; i < 4; i++) af[i] = ldsrd(Al, wm*128 + i*16 + l15, 1, lq);
    stage(Bg, K2, ktb, Bsn, 2, tid);
    stage(Bg, K2, ktb, Bsn, 3, tid);
    __builtin_amdgcn_s_setprio(1);
    #pragma unroll
    for (int mi = 0; mi < 4; mi++)
      #pragma unroll
      for (int ni = 0; ni < 4; ni++)
        acc[mi][ni] = __builtin_amdgcn_mfma_f32_16x16x32_bf16(af[mi], bf1[ni], acc[mi][ni], 0, 0, 0);
    __builtin_amdgcn_s_setprio(0);

    GATE(4);
    // ---- phase 3: ks0, mh1 ----
    #pragma unroll
    for (int i = 0; i < 4; i++) af[i] = ldsrd(Al, wm*128 + 64 + i*16 + l15, 0, lq);
    stage(Ag, K2, ktb, Asn, 0, tid);
    stage(Ag, K2, ktb, Asn, 2, tid);
    __builtin_amdgcn_s_setprio(1);
    #pragma unroll
    for (int mi = 0; mi < 4; mi++)
      #pragma unroll
      for (int ni = 0; ni < 4; ni++)
        acc[4+mi][ni] = __builtin_amdgcn_mfma_f32_16x16x32_bf16(af[mi], bf0[ni], acc[4+mi][ni], 0, 0, 0);
    __builtin_amdgcn_s_setprio(0);
    // ---- phase 4: ks1, mh1 ----
    #pragma unroll
    for (int i = 0; i < 4; i++) af[i] = ldsrd(Al, wm*128 + 64 + i*16 + l15, 1, lq);
    stage(Ag, K2, ktb, Asn, 1, tid);
    stage(Ag, K2, ktb, Asn, 3, tid);
    __builtin_amdgcn_s_setprio(1);
    #pragma unroll
    for (int mi = 0; mi < 4; mi++)
      #pragma unroll
      for (int ni = 0; ni < 4; ni++)
        acc[4+mi][ni] = __builtin_amdgcn_mfma_f32_16x16x32_bf16(af[mi], bf1[ni], acc[4+mi][ni], 0, 0, 0);
    __builtin_amdgcn_s_setprio(0);
  }
  asm volatile("s_waitcnt vmcnt(0)" ::: "memory");   // drain tail staging before exit

  if (EPI == 0) {
    #pragma unroll
    for (int mi = 0; mi < 8; mi++) {
      int row = bM*256 + wm*128 + mi*16 + lq*4;
      #pragma unroll
      for (int ni = 0; ni < 4; ni++) {
        int col = bN*256 + wn*64 + ni*16 + l15;
        #pragma unroll
        for (int r = 0; r < 4; r++)
          Cout[(size_t)(row + r) * N + col] = acc[mi][ni][r];
      }
    }
  } else {
    // block-uniform segment (0=K,1=V,2=Q) and head (cbase%128 in {0,64})
    const int cbase = bN*256 + wn*64;
    const int seg  = cbase >> 11;
    const int head = (cbase >> 7) & 15;
    #pragma unroll
    for (int mi = 0; mi < 8; mi++) {
      #pragma unroll
      for (int ni = 0; ni < 4; ni++) {
        int col = cbase + ni*16 + l15;
        int d = col & 127;
        float bi = bias[col];
        f32x4 v = acc[mi][ni];
        #pragma unroll
        for (int r = 0; r < 4; r++) {
          int n = bM*256 + wm*128 + mi*16 + lq*4 + r;   // flat token = t*B + b
          float val = v[r] + bi;
          int t = n >> 1, b = n & 1;
          int bh = b*NHEAD + head;
          if (seg == 1) {
            Vt[((size_t)bh*HD + d)*T_SEQ + t] = f2bf(val);
          } else {
            // RoPE: reference's flat reshape makes angle row = n % T
            float par = __shfl_xor(val, 1);
            int fidx = d >> 1;
            float cs = cosT[(n & (T_SEQ-1))*64 + fidx];
            float sn = sinT[(n & (T_SEQ-1))*64 + fidx];
            val = (d & 1) ? (par*sn + val*cs) : (val*cs - par*sn);
            val *= SCALE;
            u16* dst = (seg == 0) ? Kh : Qh;
            dst[((size_t)bh*T_SEQ + t)*HD + d] = f2bf(val);
          }
        }
      }
    }
  }
}

// ---------------- causal flash attention, bf16 MFMA ----------------
// 1D grid of 1024 blocks, work-balanced remap: each CU-residue class
// {c, c+256, c+512, c+768} gets qb multiset {b, 31-b, b, 31-b} = 66 tiles.
// LDS exactly 40960B -> 4 blocks/CU, whole grid co-resident, no tail.
__global__ __launch_bounds__(256, 4) void attn_fwd(
    const u16* __restrict__ Qh, const u16* __restrict__ Kh,
    const u16* __restrict__ Vt, u16* __restrict__ O)
{
  const int i = blockIdx.x;
  const int kk = i >> 8, c = i & 255;
  const int bh = (c >> 5) + kk * 8;
  const int b5 = c & 31;
  const int qb = (kk & 1) ? (31 - b5) : b5;

  const int tid = threadIdx.x, lane = tid & 63, w = tid >> 6;
  const int l15 = lane & 15, lq = lane >> 4;

  __shared__ u16 Ks[64*128];      // 16384B, swizzled
  __shared__ u16 Vs[128*64];      // 16384B, swizzled
  __shared__ char Ps[4][2048];    // 8192B: per-wave 16 rows x 128B, XOR-swizzled

  const int q0 = qb*64 + w*16;
  bf16x8 qf[4];
  #pragma unroll
  for (int dc = 0; dc < 4; dc++)
    qf[dc] = *(const bf16x8*)(Qh + ((size_t)bh*T_SEQ + q0 + l15)*HD + dc*32 + lq*8);

  f32x4 o[8] = {};
  float m[4], l_[4];
  #pragma unroll
  for (int r = 0; r < 4; r++) { m[r] = -1e30f; l_[r] = 0.f; }

  const int nkb = qb + 1;
  for (int kb = 0; kb < nkb; ++kb) {
    #pragma unroll
    for (int j = 0; j < 4; j++) {
      int lb = tid*16 + j*4096;
      int row = lb >> 8, bir = lb & 255;
      int sb = bir ^ ((row & 7) << 4);
      gld16((const char*)Kh + (((size_t)bh*T_SEQ + kb*64 + row) << 8) + sb,
            (char*)Ks + lb);
    }
    #pragma unroll
    for (int j = 0; j < 4; j++) {
      int lb = tid*16 + j*4096;
      int row = lb >> 7, bir = lb & 127;
      int sb = bir ^ ((row & 7) << 4);
      gld16((const char*)Vt + ((size_t)(bh*HD + row)*T_SEQ)*2 + kb*128 + sb,
            (char*)Vs + lb);
    }
    __syncthreads();

    // S = Q K^T  (16 q x 64 keys per wave)
    f32x4 sacc[4];
    #pragma unroll
    for (int nf = 0; nf < 4; nf++) {
      f32x4 z = {};
      sacc[nf] = z;
      #pragma unroll
      for (int dc = 0; dc < 4; dc++) {
        int row = nf*16 + l15;
        int bir = (dc*64 + lq*16) ^ ((row & 7) << 4);
        bf16x8 kf = *(const bf16x8*)((const char*)Ks + row*256 + bir);
        sacc[nf] = __builtin_amdgcn_mfma_f32_16x16x32_bf16(qf[dc], kf, sacc[nf], 0, 0, 0);
      }
    }

    if (kb == qb) {   // diagonal block: causal mask
      #pragma unroll
      for (int nf = 0; nf < 4; nf++)
        #pragma unroll
        for (int r = 0; r < 4; r++) {
          int key = kb*64 + nf*16 + l15;
          int qr  = q0 + lq*4 + r;
          if (key > qr) sacc[nf][r] = -1e30f;
        }
    }

    // online softmax (row q = q0+lq*4+r lives in 16 lanes of same lq)
    #pragma unroll
    for (int r = 0; r < 4; r++) {
      float mx = fmaxf(fmaxf(sacc[0][r], sacc[1][r]), fmaxf(sacc[2][r], sacc[3][r]));
      mx = fmaxf(mx, __shfl_xor(mx, 1));
      mx = fmaxf(mx, __shfl_xor(mx, 2));
      mx = fmaxf(mx, __shfl_xor(mx, 4));
      mx = fmaxf(mx, __shfl_xor(mx, 8));
      float newm = fmaxf(m[r], mx);
      float scale = exp2f((m[r] - newm) * LOG2E);
      float sum = 0.f;
      #pragma unroll
      for (int nf = 0; nf < 4; nf++) {
        float p = exp2f((sacc[nf][r] - newm) * LOG2E);
        sacc[nf][r] = p;
        sum += p;
      }
      sum += __shfl_xor(sum, 1);
      sum += __shfl_xor(sum, 2);
      sum += __shfl_xor(sum, 4);
      sum += __shfl_xor(sum, 8);
      l_[r] = l_[r] * scale + sum;
      m[r] = newm;
      #pragma unroll
      for (int nf = 0; nf < 8; nf++) o[nf][r] *= scale;
    }

    // P -> bf16 tile in wave-private LDS slab, XOR-swizzled rows (128B row)
    #pragma unroll
    for (int nf = 0; nf < 4; nf++)
      #pragma unroll
      for (int r = 0; r < 4; r++) {
        int prow = lq*4 + r;
        int pbyte = prow*128 + ((((nf*16 + l15)*2)) ^ ((prow & 7) << 4));
        *(u16*)(Ps[w] + pbyte) = f2bf(sacc[nf][r]);
      }

    // O += P V   (A-frag from Ps, B-frag from swizzled Vs)
    #pragma unroll
    for (int kc = 0; kc < 2; kc++) {
      int pb = (kc*64 + lq*16) ^ ((l15 & 7) << 4);
      bf16x8 pf = *(const bf16x8*)(Ps[w] + l15*128 + pb);
      #pragma unroll
      for (int nf = 0; nf < 8; nf++) {
        int row = nf*16 + l15;
        int bir = (kc*64 + lq*16) ^ ((row & 7) << 4);
        bf16x8 vf = *(const bf16x8*)((const char*)Vs + row*128 + bir);
        o[nf] = __builtin_amdgcn_mfma_f32_16x16x32_bf16(pf, vf, o[nf], 0, 0, 0);
      }
    }
    __syncthreads();
  }

  // epilogue: O row -> [t*B+b][h*D+d] bf16 for the output GEMM
  const int b = bh >> 4, h = bh & 15;
  #pragma unroll
  for (int r = 0; r < 4; r++) {
    float inv = 1.0f / l_[r];
    int t = q0 + lq*4 + r;
    size_t base = ((size_t)(t*2 + b))*EMB + h*HD;
    #pragma unroll
    for (int nf = 0; nf < 8; nf++)
      O[base + nf*16 + l15] = f2bf(o[nf][r] * inv);
  }
}

// ---------------- launch ----------------
extern "C" void kernel_launch(void* const* d_in, const int* in_sizes, int n_in,
                              void* d_out, int out_size, void* d_ws, size_t ws_size,
                              hipStream_t stream) {
  const float* query = (const float*)d_in[0];
  const float* Wqkv  = (const float*)d_in[1];
  const float* bqkv  = (const float*)d_in[2];
  const float* Wo    = (const float*)d_in[3];
  // d_in[4] = bo — reference does NOT add it
  const float* fcos  = (const float*)d_in[5];
  const float* fsin  = (const float*)d_in[6];
  float* out = (float*)d_out;
  char* ws = (char*)d_ws;

  // workspace layout (bytes), total 96MB
  u16* WQb = (u16*)(ws + 0);          // 6144x2048 bf16 = 25165824
  u16* WOb = (u16*)(ws + 25165824);   // 2048x2048 bf16 =  8388608
  u16* A1  = (u16*)(ws + 33554432);   // 4096x2048 bf16 (query; reused as attn out)
  u16* QH  = (u16*)(ws + 50331648);   // [32][2048][128] bf16
  u16* KH  = (u16*)(ws + 67108864);
  u16* VT  = (u16*)(ws + 83886080);   // [32][128][2048] bf16  (end: 100663296)

  cvt_bf16<<<4096, 256, 0, stream>>>(query, A1, 1048576);
  cvt_bf16<<<6144, 256, 0, stream>>>(Wqkv, WQb, 1572864);
  cvt_bf16<<<2048, 256, 0, stream>>>(Wo,   WOb,  524288);

  gemm8<1, 24><<<384, 512, 0, stream>>>(A1, WQb, 2048, NE3,
                                        fcos, fsin, bqkv, QH, KH, VT, nullptr);

  attn_fwd<<<1024, 256, 0, stream>>>(QH, KH, VT, A1);

  gemm8<0, 8><<<128, 512, 0, stream>>>(A1, WOb, 2048, EMB,
                                       nullptr, nullptr, nullptr,
                                       nullptr, nullptr, nullptr, out);
}

// Round 5
// 350.031 us; speedup vs baseline: 1.1479x; 1.0268x over previous
//
#include <hip/hip_runtime.h>
#include <stdint.h>

typedef unsigned short u16;
typedef __attribute__((ext_vector_type(4))) float f32x4;
typedef __attribute__((ext_vector_type(8))) short bf16x8;
typedef __attribute__((ext_vector_type(8))) u16 u16x8;

#define T_SEQ  2048
#define EMB    2048
#define HD     128
#define NHEAD  16
#define NTOK   4096
#define NE3    6144
#define SCALE  0.29730177875068026f   // 128^-0.25
#define LOG2E  1.44269504088896f

typedef __attribute__((address_space(3))) char* lds_t;
typedef const __attribute__((address_space(1))) char* gl_t;

__device__ __forceinline__ void gld16(const void* g, void* l) {
  __builtin_amdgcn_global_load_lds((gl_t)g, (lds_t)l, 16, 0, 0);
}

__device__ __forceinline__ u16 f2bf(float f) {
  union { float f; uint32_t u; } c; c.f = f;
  uint32_t r = c.u + 0x7fffu + ((c.u >> 16) & 1u);
  return (u16)(r >> 16);
}

// ---------------- fp32 -> bf16 conversion (memory-bound) ----------------
__global__ __launch_bounds__(256) void cvt_bf16(const float* __restrict__ in,
                                                u16* __restrict__ out, int n8) {
  int i = blockIdx.x * 256 + threadIdx.x;
  if (i >= n8) return;
  const float4* p = (const float4*)in + (size_t)i * 2;
  float4 a = p[0], b = p[1];
  u16x8 o;
  o[0]=f2bf(a.x); o[1]=f2bf(a.y); o[2]=f2bf(a.z); o[3]=f2bf(a.w);
  o[4]=f2bf(b.x); o[5]=f2bf(b.y); o[6]=f2bf(b.z); o[7]=f2bf(b.w);
  *((u16x8*)out + i) = o;
}

// ======== 128x256 uniform-phase pipelined bf16 GEMM, B^T layout ========
// C[m][n] = sum_k A[m][k]*Bm[n][k].  8 waves (2M x 4N), wave tile 64x64.
// LDS = 8 K-half slots: A 4x8KB @0, B 4x16KB @32768 (96KB total).
// Slot(mat, tile-parity tp, ks) holds [rows][32 k] with col' = c ^ ((row>>1)&3)
// swizzle (read and staged-source use the same involution).
// Phase q (q=2t+ks): vmcnt(6); barrier; ds_read 4A+4B frags; stage pair for
// phase q+3 into slot freed at q-1 (3 gld16/thread); lgkmcnt(0); 16 MFMA.
// Ledger: every phase's pair was staged 3 phases earlier with 6 loads issued
// since -> uniform vmcnt(6), queue never drains. Prologue = 3 pairs.

__device__ __forceinline__ bf16x8 rdfrag(const char* slot, int row, int lq) {
  return *(const bf16x8*)(slot + row*64 + ((lq ^ ((row >> 1) & 3)) << 4));
}
__device__ __forceinline__ void stageA(const char* Ag, int K2, int ktb, int ks,
                                       char* slot, int tid) {
  int row = tid >> 2, c = tid & 3;
  gld16(Ag + (size_t)row*K2 + ktb + ks*64 + ((c ^ ((row >> 1) & 3)) << 4),
        slot + tid*16);
}
__device__ __forceinline__ void stageB(const char* Bg, int K2, int ktb, int ks,
                                       char* slot, int j, int tid) {
  int lb = j*8192 + tid*16;
  int row = lb >> 6, c = (lb >> 4) & 3;
  gld16(Bg + (size_t)row*K2 + ktb + ks*64 + ((c ^ ((row >> 1) & 3)) << 4),
        slot + lb);
}

template<int EPI, int NBN>
__global__ __launch_bounds__(512, 2) void gemmP(
    const u16* __restrict__ A, const u16* __restrict__ Bm, int K, int N,
    const float* __restrict__ cosT, const float* __restrict__ sinT,
    const float* __restrict__ bias,
    u16* __restrict__ Qh, u16* __restrict__ Kh, u16* __restrict__ Vt,
    float* __restrict__ Cout)
{
  __shared__ __align__(16) char lds[98304];
  const int tid = threadIdx.x;
  const int lane = tid & 63, w = tid >> 6;
  const int wm = w >> 2, wn = w & 3;      // 2M x 4N waves
  const int l15 = lane & 15, lq = lane >> 4;

  // bijective XCD swizzle (gridDim.x % 8 == 0 at both call sites)
  const int q8 = gridDim.x >> 3;
  const int swz = (blockIdx.x & 7) * q8 + (blockIdx.x >> 3);
  const int bM = swz / NBN, bN = swz % NBN;

  const char* Ag = (const char*)(A + (size_t)bM * 128 * K);
  const char* Bg = (const char*)(Bm + (size_t)bN * 256 * K);
  const int K2 = K * 2;
  const int nT = K >> 6;

  // prologue: pairs (t0,ks0),(t0,ks1),(t1,ks0) = 9 loads/thread
  stageA(Ag, K2, 0,   0, lds + 0,     tid);
  stageB(Bg, K2, 0,   0, lds + 32768, 0, tid);
  stageB(Bg, K2, 0,   0, lds + 32768, 1, tid);
  stageA(Ag, K2, 0,   1, lds + 8192,  tid);
  stageB(Bg, K2, 0,   1, lds + 49152, 0, tid);
  stageB(Bg, K2, 0,   1, lds + 49152, 1, tid);
  stageA(Ag, K2, 128, 0, lds + 16384, tid);
  stageB(Bg, K2, 128, 0, lds + 65536, 0, tid);
  stageB(Bg, K2, 128, 0, lds + 65536, 1, tid);

  f32x4 acc[4][4] = {};

  for (int t = 0; t < nT; ++t) {
    #pragma unroll
    for (int ks = 0; ks < 2; ++ks) {
      const int q = 2*t + ks;
      const int ts = (q + 3) >> 1, kss = (q + 3) & 1;
      const int tsc = ts < nT ? ts : nT - 1;       // tail: re-stage (unread)
      const char* Asl = lds + ((t & 1)*2 + ks)*8192;
      const char* Bsl = lds + 32768 + ((t & 1)*2 + ks)*16384;
      char* AslS = lds + ((ts & 1)*2 + kss)*8192;
      char* BslS = lds + 32768 + ((ts & 1)*2 + kss)*16384;

      asm volatile("s_waitcnt vmcnt(6)" ::: "memory");
      __builtin_amdgcn_s_barrier();
      __builtin_amdgcn_sched_barrier(0);

      bf16x8 af[4], bf[4];
      #pragma unroll
      for (int i = 0; i < 4; i++) af[i] = rdfrag(Asl, wm*64 + i*16 + l15, lq);
      #pragma unroll
      for (int i = 0; i < 4; i++) bf[i] = rdfrag(Bsl, wn*64 + i*16 + l15, lq);
      stageA(Ag, K2, tsc << 7, kss, AslS, tid);
      stageB(Bg, K2, tsc << 7, kss, BslS, 0, tid);
      stageB(Bg, K2, tsc << 7, kss, BslS, 1, tid);
      asm volatile("s_waitcnt lgkmcnt(0)" ::: "memory");
      __builtin_amdgcn_sched_barrier(0);
      __builtin_amdgcn_s_setprio(1);
      #pragma unroll
      for (int mi = 0; mi < 4; mi++)
        #pragma unroll
        for (int ni = 0; ni < 4; ni++)
          acc[mi][ni] = __builtin_amdgcn_mfma_f32_16x16x32_bf16(af[mi], bf[ni], acc[mi][ni], 0, 0, 0);
      __builtin_amdgcn_s_setprio(0);
    }
  }
  asm volatile("s_waitcnt vmcnt(0)" ::: "memory");   // drain tail staging

  if (EPI == 0) {
    #pragma unroll
    for (int mi = 0; mi < 4; mi++) {
      int row = bM*128 + wm*64 + mi*16 + lq*4;
      #pragma unroll
      for (int ni = 0; ni < 4; ni++) {
        int col = bN*256 + wn*64 + ni*16 + l15;
        #pragma unroll
        for (int r = 0; r < 4; r++)
          Cout[(size_t)(row + r) * N + col] = acc[mi][ni][r];
      }
    }
  } else {
    // block-uniform segment (0=K,1=V,2=Q) and head (cbase%128 in {0,64})
    const int cbase = bN*256 + wn*64;
    const int seg  = cbase >> 11;
    const int head = (cbase >> 7) & 15;
    #pragma unroll
    for (int mi = 0; mi < 4; mi++) {
      #pragma unroll
      for (int ni = 0; ni < 4; ni++) {
        int col = cbase + ni*16 + l15;
        int d = col & 127;
        float bi = bias[col];
        f32x4 v = acc[mi][ni];
        #pragma unroll
        for (int r = 0; r < 4; r++) {
          int n = bM*128 + wm*64 + mi*16 + lq*4 + r;   // flat token = t*B + b
          float val = v[r] + bi;
          int t = n >> 1, b = n & 1;
          int bh = b*NHEAD + head;
          if (seg == 1) {
            Vt[((size_t)bh*HD + d)*T_SEQ + t] = f2bf(val);
          } else {
            // RoPE: reference's flat reshape makes angle row = n % T
            float par = __shfl_xor(val, 1);
            int fidx = d >> 1;
            float cs = cosT[(n & (T_SEQ-1))*64 + fidx];
            float sn = sinT[(n & (T_SEQ-1))*64 + fidx];
            val = (d & 1) ? (par*sn + val*cs) : (val*cs - par*sn);
            val *= SCALE;
            u16* dst = (seg == 0) ? Kh : Qh;
            dst[((size_t)bh*T_SEQ + t)*HD + d] = f2bf(val);
          }
        }
      }
    }
  }
}

// ---------------- causal flash attention, bf16 MFMA ----------------
// 1D grid of 1024 blocks, work-balanced remap: each CU-residue class
// {c, c+256, c+512, c+768} gets qb multiset {b, 31-b, b, 31-b} = 66 tiles.
// LDS exactly 40960B -> 4 blocks/CU, whole grid co-resident, no tail.
__global__ __launch_bounds__(256, 4) void attn_fwd(
    const u16* __restrict__ Qh, const u16* __restrict__ Kh,
    const u16* __restrict__ Vt, u16* __restrict__ O)
{
  const int i = blockIdx.x;
  const int kk = i >> 8, c = i & 255;
  const int bh = (c >> 5) + kk * 8;
  const int b5 = c & 31;
  const int qb = (kk & 1) ? (31 - b5) : b5;

  const int tid = threadIdx.x, lane = tid & 63, w = tid >> 6;
  const int l15 = lane & 15, lq = lane >> 4;

  __shared__ u16 Ks[64*128];      // 16384B, swizzled
  __shared__ u16 Vs[128*64];      // 16384B, swizzled
  __shared__ char Ps[4][2048];    // 8192B: per-wave 16 rows x 128B, XOR-swizzled

  const int q0 = qb*64 + w*16;
  bf16x8 qf[4];
  #pragma unroll
  for (int dc = 0; dc < 4; dc++)
    qf[dc] = *(const bf16x8*)(Qh + ((size_t)bh*T_SEQ + q0 + l15)*HD + dc*32 + lq*8);

  f32x4 o[8] = {};
  float m[4], l_[4];
  #pragma unroll
  for (int r = 0; r < 4; r++) { m[r] = -1e30f; l_[r] = 0.f; }

  const int nkb = qb + 1;
  for (int kb = 0; kb < nkb; ++kb) {
    #pragma unroll
    for (int j = 0; j < 4; j++) {
      int lb = tid*16 + j*4096;
      int row = lb >> 8, bir = lb & 255;
      int sb = bir ^ ((row & 7) << 4);
      gld16((const char*)Kh + (((size_t)bh*T_SEQ + kb*64 + row) << 8) + sb,
            (char*)Ks + lb);
    }
    #pragma unroll
    for (int j = 0; j < 4; j++) {
      int lb = tid*16 + j*4096;
      int row = lb >> 7, bir = lb & 127;
      int sb = bir ^ ((row & 7) << 4);
      gld16((const char*)Vt + ((size_t)(bh*HD + row)*T_SEQ)*2 + kb*128 + sb,
            (char*)Vs + lb);
    }
    __syncthreads();

    // S = Q K^T  (16 q x 64 keys per wave)
    f32x4 sacc[4];
    #pragma unroll
    for (int nf = 0; nf < 4; nf++) {
      f32x4 z = {};
      sacc[nf] = z;
      #pragma unroll
      for (int dc = 0; dc < 4; dc++) {
        int row = nf*16 + l15;
        int bir = (dc*64 + lq*16) ^ ((row & 7) << 4);
        bf16x8 kf = *(const bf16x8*)((const char*)Ks + row*256 + bir);
        sacc[nf] = __builtin_amdgcn_mfma_f32_16x16x32_bf16(qf[dc], kf, sacc[nf], 0, 0, 0);
      }
    }

    if (kb == qb) {   // diagonal block: causal mask
      #pragma unroll
      for (int nf = 0; nf < 4; nf++)
        #pragma unroll
        for (int r = 0; r < 4; r++) {
          int key = kb*64 + nf*16 + l15;
          int qr  = q0 + lq*4 + r;
          if (key > qr) sacc[nf][r] = -1e30f;
        }
    }

    // online softmax (row q = q0+lq*4+r lives in 16 lanes of same lq)
    #pragma unroll
    for (int r = 0; r < 4; r++) {
      float mx = fmaxf(fmaxf(sacc[0][r], sacc[1][r]), fmaxf(sacc[2][r], sacc[3][r]));
      mx = fmaxf(mx, __shfl_xor(mx, 1));
      mx = fmaxf(mx, __shfl_xor(mx, 2));
      mx = fmaxf(mx, __shfl_xor(mx, 4));
      mx = fmaxf(mx, __shfl_xor(mx, 8));
      float newm = fmaxf(m[r], mx);
      float scale = exp2f((m[r] - newm) * LOG2E);
      float sum = 0.f;
      #pragma unroll
      for (int nf = 0; nf < 4; nf++) {
        float p = exp2f((sacc[nf][r] - newm) * LOG2E);
        sacc[nf][r] = p;
        sum += p;
      }
      sum += __shfl_xor(sum, 1);
      sum += __shfl_xor(sum, 2);
      sum += __shfl_xor(sum, 4);
      sum += __shfl_xor(sum, 8);
      l_[r] = l_[r] * scale + sum;
      m[r] = newm;
      #pragma unroll
      for (int nf = 0; nf < 8; nf++) o[nf][r] *= scale;
    }

    // P -> bf16 tile in wave-private LDS slab, XOR-swizzled rows (128B row)
    #pragma unroll
    for (int nf = 0; nf < 4; nf++)
      #pragma unroll
      for (int r = 0; r < 4; r++) {
        int prow = lq*4 + r;
        int pbyte = prow*128 + ((((nf*16 + l15)*2)) ^ ((prow & 7) << 4));
        *(u16*)(Ps[w] + pbyte) = f2bf(sacc[nf][r]);
      }

    // O += P V   (A-frag from Ps, B-frag from swizzled Vs)
    #pragma unroll
    for (int kc = 0; kc < 2; kc++) {
      int pb = (kc*64 + lq*16) ^ ((l15 & 7) << 4);
      bf16x8 pf = *(const bf16x8*)(Ps[w] + l15*128 + pb);
      #pragma unroll
      for (int nf = 0; nf < 8; nf++) {
        int row = nf*16 + l15;
        int bir = (kc*64 + lq*16) ^ ((row & 7) << 4);
        bf16x8 vf = *(const bf16x8*)((const char*)Vs + row*128 + bir);
        o[nf] = __builtin_amdgcn_mfma_f32_16x16x32_bf16(pf, vf, o[nf], 0, 0, 0);
      }
    }
    __syncthreads();
  }

  // epilogue: O row -> [t*B+b][h*D+d] bf16 for the output GEMM
  const int b = bh >> 4, h = bh & 15;
  #pragma unroll
  for (int r = 0; r < 4; r++) {
    float inv = 1.0f / l_[r];
    int t = q0 + lq*4 + r;
    size_t base = ((size_t)(t*2 + b))*EMB + h*HD;
    #pragma unroll
    for (int nf = 0; nf < 8; nf++)
      O[base + nf*16 + l15] = f2bf(o[nf][r] * inv);
  }
}

// ---------------- launch ----------------
extern "C" void kernel_launch(void* const* d_in, const int* in_sizes, int n_in,
                              void* d_out, int out_size, void* d_ws, size_t ws_size,
                              hipStream_t stream) {
  const float* query = (const float*)d_in[0];
  const float* Wqkv  = (const float*)d_in[1];
  const float* bqkv  = (const float*)d_in[2];
  const float* Wo    = (const float*)d_in[3];
  // d_in[4] = bo — reference does NOT add it
  const float* fcos  = (const float*)d_in[5];
  const float* fsin  = (const float*)d_in[6];
  float* out = (float*)d_out;
  char* ws = (char*)d_ws;

  // workspace layout (bytes), total 96MB
  u16* WQb = (u16*)(ws + 0);          // 6144x2048 bf16 = 25165824
  u16* WOb = (u16*)(ws + 25165824);   // 2048x2048 bf16 =  8388608
  u16* A1  = (u16*)(ws + 33554432);   // 4096x2048 bf16 (query; reused as attn out)
  u16* QH  = (u16*)(ws + 50331648);   // [32][2048][128] bf16
  u16* KH  = (u16*)(ws + 67108864);
  u16* VT  = (u16*)(ws + 83886080);   // [32][128][2048] bf16  (end: 100663296)

  cvt_bf16<<<4096, 256, 0, stream>>>(query, A1, 1048576);
  cvt_bf16<<<6144, 256, 0, stream>>>(Wqkv, WQb, 1572864);
  cvt_bf16<<<2048, 256, 0, stream>>>(Wo,   WOb,  524288);

  gemmP<1, 24><<<768, 512, 0, stream>>>(A1, WQb, 2048, NE3,
                                        fcos, fsin, bqkv, QH, KH, VT, nullptr);

  attn_fwd<<<1024, 256, 0, stream>>>(QH, KH, VT, A1);

  gemmP<0, 8><<<256, 512, 0, stream>>>(A1, WOb, 2048, EMB,
                                       nullptr, nullptr, nullptr,
                                       nullptr, nullptr, nullptr, out);
}

// Round 6
// 340.930 us; speedup vs baseline: 1.1785x; 1.0267x over previous
//
#include <hip/hip_runtime.h>
#include <stdint.h>

typedef unsigned short u16;
typedef __attribute__((ext_vector_type(4))) float f32x4;
typedef __attribute__((ext_vector_type(8))) short bf16x8;
typedef __attribute__((ext_vector_type(8))) u16 u16x8;

#define T_SEQ  2048
#define EMB    2048
#define HD     128
#define NHEAD  16
#define NTOK   4096
#define NE3    6144
#define SCALE  0.29730177875068026f   // 128^-0.25
#define LOG2E  1.44269504088896f

typedef __attribute__((address_space(3))) char* lds_t;
typedef const __attribute__((address_space(1))) char* gl_t;

__device__ __forceinline__ void gld16(const void* g, void* l) {
  __builtin_amdgcn_global_load_lds((gl_t)g, (lds_t)l, 16, 0, 0);
}

__device__ __forceinline__ u16 f2bf(float f) {
  union { float f; uint32_t u; } c; c.f = f;
  uint32_t r = c.u + 0x7fffu + ((c.u >> 16) & 1u);
  return (u16)(r >> 16);
}

// ---------------- fp32 -> bf16 conversion (memory-bound) ----------------
__global__ __launch_bounds__(256) void cvt_bf16(const float* __restrict__ in,
                                                u16* __restrict__ out, int n8) {
  int i = blockIdx.x * 256 + threadIdx.x;
  if (i >= n8) return;
  const float4* p = (const float4*)in + (size_t)i * 2;
  float4 a = p[0], b = p[1];
  u16x8 o;
  o[0]=f2bf(a.x); o[1]=f2bf(a.y); o[2]=f2bf(a.z); o[3]=f2bf(a.w);
  o[4]=f2bf(b.x); o[5]=f2bf(b.y); o[6]=f2bf(b.z); o[7]=f2bf(b.w);
  *((u16x8*)out + i) = o;
}

// ======== 128x256 uniform-phase pipelined bf16 GEMM, B^T layout ========
// Supertile mapping: block i -> r=i>>8, x=i&7 (XCD heuristic), s=(i>>3)&31.
// regionId=r*8+x -> RM=regionId&3 (8 bM rows), RN=regionId>>2 (4 bN cols).
// Each XCD's 32 concurrent blocks = compact 8x4 region: A 4MB + B 4MB stream
// K-lockstep through its private L2 -> HBM fetch ~= first touch only.
// Pipeline: 6 LDS slots per matrix (A 6x8KB, B 6x16KB = 144KB), prefetch
// depth 5 pairs, uniform gate vmcnt(12) per phase (5 pairs x 3 loads in
// flight, oldest pair completes). Phase = 16 MFMA per wave.

__device__ __forceinline__ bf16x8 rdfrag(const char* slot, int row, int lq) {
  return *(const bf16x8*)(slot + row*64 + ((lq ^ ((row >> 1) & 3)) << 4));
}
__device__ __forceinline__ void stageA(const char* Ag, int K2, int ktb, int ks,
                                       char* slot, int tid) {
  int row = tid >> 2, c = tid & 3;
  gld16(Ag + (size_t)row*K2 + ktb + ks*64 + ((c ^ ((row >> 1) & 3)) << 4),
        slot + tid*16);
}
__device__ __forceinline__ void stageB(const char* Bg, int K2, int ktb, int ks,
                                       char* slot, int j, int tid) {
  int lb = j*8192 + tid*16;
  int row = lb >> 6, c = (lb >> 4) & 3;
  gld16(Bg + (size_t)row*K2 + ktb + ks*64 + ((c ^ ((row >> 1) & 3)) << 4),
        slot + lb);
}

template<int EPI, int NBN>
__global__ __launch_bounds__(512, 2) void gemmP(
    const u16* __restrict__ A, const u16* __restrict__ Bm, int K, int N,
    const float* __restrict__ cosT, const float* __restrict__ sinT,
    const float* __restrict__ bias,
    u16* __restrict__ Qh, u16* __restrict__ Kh, u16* __restrict__ Vt,
    float* __restrict__ Cout)
{
  __shared__ __align__(16) char lds[147456];   // A slots 0..49151, B 49152..
  const int tid = threadIdx.x;
  const int lane = tid & 63, w = tid >> 6;
  const int wm = w >> 2, wn = w & 3;      // 2M x 4N waves
  const int l15 = lane & 15, lq = lane >> 4;

  // supertile decode
  const int i = blockIdx.x;
  const int r = i >> 8, x = i & 7, s = (i >> 3) & 31;
  const int regionId = r*8 + x;
  const int RM = regionId & 3, RN = regionId >> 2;
  const int bM = RM*8 + (s >> 2);
  const int bN = RN*4 + (s & 3);

  const char* Ag = (const char*)(A + (size_t)bM * 128 * K);
  const char* Bg = (const char*)(Bm + (size_t)bN * 256 * K);
  const int K2 = K * 2;
  const int nT = K >> 6;
  const int nQ = 2*nT;

  // prologue: stage pairs for phases 0..4 into slots 0..4
  #pragma unroll
  for (int q = 0; q < 5; ++q) {
    int kt = (q >> 1) << 7, ks = q & 1;
    stageA(Ag, K2, kt, ks, lds + q*8192, tid);
    stageB(Bg, K2, kt, ks, lds + 49152 + q*16384, 0, tid);
    stageB(Bg, K2, kt, ks, lds + 49152 + q*16384, 1, tid);
  }

  f32x4 acc[4][4] = {};
  int sRd = 0, sWr = 5;

  for (int q = 0; q < nQ; ++q) {
    const int qs = q + 5;
    const int tsc = (qs >> 1) < nT ? (qs >> 1) : nT - 1;  // tail: re-stage
    const int kss = qs & 1;
    const char* Asl = lds + sRd*8192;
    const char* Bsl = lds + 49152 + sRd*16384;
    char* AslS = lds + sWr*8192;
    char* BslS = lds + 49152 + sWr*16384;

    asm volatile("s_waitcnt vmcnt(12)" ::: "memory");
    __builtin_amdgcn_s_barrier();
    __builtin_amdgcn_sched_barrier(0);

    bf16x8 af[4], bf[4];
    #pragma unroll
    for (int j = 0; j < 4; j++) af[j] = rdfrag(Asl, wm*64 + j*16 + l15, lq);
    #pragma unroll
    for (int j = 0; j < 4; j++) bf[j] = rdfrag(Bsl, wn*64 + j*16 + l15, lq);
    stageA(Ag, K2, tsc << 7, kss, AslS, tid);
    stageB(Bg, K2, tsc << 7, kss, BslS, 0, tid);
    stageB(Bg, K2, tsc << 7, kss, BslS, 1, tid);
    asm volatile("s_waitcnt lgkmcnt(0)" ::: "memory");
    __builtin_amdgcn_sched_barrier(0);
    __builtin_amdgcn_s_setprio(1);
    #pragma unroll
    for (int mi = 0; mi < 4; mi++)
      #pragma unroll
      for (int ni = 0; ni < 4; ni++)
        acc[mi][ni] = __builtin_amdgcn_mfma_f32_16x16x32_bf16(af[mi], bf[ni], acc[mi][ni], 0, 0, 0);
    __builtin_amdgcn_s_setprio(0);

    sRd = sRd + 1 < 6 ? sRd + 1 : 0;
    sWr = sWr + 1 < 6 ? sWr + 1 : 0;
  }
  asm volatile("s_waitcnt vmcnt(0)" ::: "memory");   // drain tail staging

  if (EPI == 0) {
    #pragma unroll
    for (int mi = 0; mi < 4; mi++) {
      int row = bM*128 + wm*64 + mi*16 + lq*4;
      #pragma unroll
      for (int ni = 0; ni < 4; ni++) {
        int col = bN*256 + wn*64 + ni*16 + l15;
        #pragma unroll
        for (int rr = 0; rr < 4; rr++)
          Cout[(size_t)(row + rr) * N + col] = acc[mi][ni][rr];
      }
    }
  } else {
    // block-uniform segment (0=K,1=V,2=Q) and head (cbase%128 in {0,64})
    const int cbase = bN*256 + wn*64;
    const int seg  = cbase >> 11;
    const int head = (cbase >> 7) & 15;
    #pragma unroll
    for (int mi = 0; mi < 4; mi++) {
      #pragma unroll
      for (int ni = 0; ni < 4; ni++) {
        int col = cbase + ni*16 + l15;
        int d = col & 127;
        float bi = bias[col];
        f32x4 v = acc[mi][ni];
        #pragma unroll
        for (int rr = 0; rr < 4; rr++) {
          int n = bM*128 + wm*64 + mi*16 + lq*4 + rr;   // flat token = t*B + b
          float val = v[rr] + bi;
          int t = n >> 1, b = n & 1;
          int bh = b*NHEAD + head;
          if (seg == 1) {
            Vt[((size_t)bh*HD + d)*T_SEQ + t] = f2bf(val);
          } else {
            // RoPE: reference's flat reshape makes angle row = n % T
            float par = __shfl_xor(val, 1);
            int fidx = d >> 1;
            float cs = cosT[(n & (T_SEQ-1))*64 + fidx];
            float sn = sinT[(n & (T_SEQ-1))*64 + fidx];
            val = (d & 1) ? (par*sn + val*cs) : (val*cs - par*sn);
            val *= SCALE;
            u16* dst = (seg == 0) ? Kh : Qh;
            dst[((size_t)bh*T_SEQ + t)*HD + d] = f2bf(val);
          }
        }
      }
    }
  }
}

// ---------------- causal flash attention, bf16 MFMA ----------------
// 1D grid of 1024 blocks, work-balanced remap: each CU-residue class
// {c, c+256, c+512, c+768} gets qb multiset {b, 31-b, b, 31-b} = 66 tiles.
// LDS exactly 40960B -> 4 blocks/CU, whole grid co-resident, no tail.
__global__ __launch_bounds__(256, 4) void attn_fwd(
    const u16* __restrict__ Qh, const u16* __restrict__ Kh,
    const u16* __restrict__ Vt, u16* __restrict__ O)
{
  const int i = blockIdx.x;
  const int kk = i >> 8, c = i & 255;
  const int bh = (c >> 5) + kk * 8;
  const int b5 = c & 31;
  const int qb = (kk & 1) ? (31 - b5) : b5;

  const int tid = threadIdx.x, lane = tid & 63, w = tid >> 6;
  const int l15 = lane & 15, lq = lane >> 4;

  __shared__ u16 Ks[64*128];      // 16384B, swizzled
  __shared__ u16 Vs[128*64];      // 16384B, swizzled
  __shared__ char Ps[4][2048];    // 8192B: per-wave 16 rows x 128B, XOR-swizzled

  const int q0 = qb*64 + w*16;
  bf16x8 qf[4];
  #pragma unroll
  for (int dc = 0; dc < 4; dc++)
    qf[dc] = *(const bf16x8*)(Qh + ((size_t)bh*T_SEQ + q0 + l15)*HD + dc*32 + lq*8);

  f32x4 o[8] = {};
  float m[4], l_[4];
  #pragma unroll
  for (int r = 0; r < 4; r++) { m[r] = -1e30f; l_[r] = 0.f; }

  const int nkb = qb + 1;
  for (int kb = 0; kb < nkb; ++kb) {
    #pragma unroll
    for (int j = 0; j < 4; j++) {
      int lb = tid*16 + j*4096;
      int row = lb >> 8, bir = lb & 255;
      int sb = bir ^ ((row & 7) << 4);
      gld16((const char*)Kh + (((size_t)bh*T_SEQ + kb*64 + row) << 8) + sb,
            (char*)Ks + lb);
    }
    #pragma unroll
    for (int j = 0; j < 4; j++) {
      int lb = tid*16 + j*4096;
      int row = lb >> 7, bir = lb & 127;
      int sb = bir ^ ((row & 7) << 4);
      gld16((const char*)Vt + ((size_t)(bh*HD + row)*T_SEQ)*2 + kb*128 + sb,
            (char*)Vs + lb);
    }
    __syncthreads();

    // S = Q K^T  (16 q x 64 keys per wave)
    f32x4 sacc[4];
    #pragma unroll
    for (int nf = 0; nf < 4; nf++) {
      f32x4 z = {};
      sacc[nf] = z;
      #pragma unroll
      for (int dc = 0; dc < 4; dc++) {
        int row = nf*16 + l15;
        int bir = (dc*64 + lq*16) ^ ((row & 7) << 4);
        bf16x8 kf = *(const bf16x8*)((const char*)Ks + row*256 + bir);
        sacc[nf] = __builtin_amdgcn_mfma_f32_16x16x32_bf16(qf[dc], kf, sacc[nf], 0, 0, 0);
      }
    }

    if (kb == qb) {   // diagonal block: causal mask
      #pragma unroll
      for (int nf = 0; nf < 4; nf++)
        #pragma unroll
        for (int r = 0; r < 4; r++) {
          int key = kb*64 + nf*16 + l15;
          int qr  = q0 + lq*4 + r;
          if (key > qr) sacc[nf][r] = -1e30f;
        }
    }

    // online softmax (row q = q0+lq*4+r lives in 16 lanes of same lq)
    #pragma unroll
    for (int r = 0; r < 4; r++) {
      float mx = fmaxf(fmaxf(sacc[0][r], sacc[1][r]), fmaxf(sacc[2][r], sacc[3][r]));
      mx = fmaxf(mx, __shfl_xor(mx, 1));
      mx = fmaxf(mx, __shfl_xor(mx, 2));
      mx = fmaxf(mx, __shfl_xor(mx, 4));
      mx = fmaxf(mx, __shfl_xor(mx, 8));
      float newm = fmaxf(m[r], mx);
      float scale = exp2f((m[r] - newm) * LOG2E);
      float sum = 0.f;
      #pragma unroll
      for (int nf = 0; nf < 4; nf++) {
        float p = exp2f((sacc[nf][r] - newm) * LOG2E);
        sacc[nf][r] = p;
        sum += p;
      }
      sum += __shfl_xor(sum, 1);
      sum += __shfl_xor(sum, 2);
      sum += __shfl_xor(sum, 4);
      sum += __shfl_xor(sum, 8);
      l_[r] = l_[r] * scale + sum;
      m[r] = newm;
      #pragma unroll
      for (int nf = 0; nf < 8; nf++) o[nf][r] *= scale;
    }

    // P -> bf16 tile in wave-private LDS slab, XOR-swizzled rows (128B row)
    #pragma unroll
    for (int nf = 0; nf < 4; nf++)
      #pragma unroll
      for (int r = 0; r < 4; r++) {
        int prow = lq*4 + r;
        int pbyte = prow*128 + ((((nf*16 + l15)*2)) ^ ((prow & 7) << 4));
        *(u16*)(Ps[w] + pbyte) = f2bf(sacc[nf][r]);
      }

    // O += P V   (A-frag from Ps, B-frag from swizzled Vs)
    #pragma unroll
    for (int kc = 0; kc < 2; kc++) {
      int pb = (kc*64 + lq*16) ^ ((l15 & 7) << 4);
      bf16x8 pf = *(const bf16x8*)(Ps[w] + l15*128 + pb);
      #pragma unroll
      for (int nf = 0; nf < 8; nf++) {
        int row = nf*16 + l15;
        int bir = (kc*64 + lq*16) ^ ((row & 7) << 4);
        bf16x8 vf = *(const bf16x8*)((const char*)Vs + row*128 + bir);
        o[nf] = __builtin_amdgcn_mfma_f32_16x16x32_bf16(pf, vf, o[nf], 0, 0, 0);
      }
    }
    __syncthreads();
  }

  // epilogue: O row -> [t*B+b][h*D+d] bf16 for the output GEMM
  const int b = bh >> 4, h = bh & 15;
  #pragma unroll
  for (int r = 0; r < 4; r++) {
    float inv = 1.0f / l_[r];
    int t = q0 + lq*4 + r;
    size_t base = ((size_t)(t*2 + b))*EMB + h*HD;
    #pragma unroll
    for (int nf = 0; nf < 8; nf++)
      O[base + nf*16 + l15] = f2bf(o[nf][r] * inv);
  }
}

// ---------------- launch ----------------
extern "C" void kernel_launch(void* const* d_in, const int* in_sizes, int n_in,
                              void* d_out, int out_size, void* d_ws, size_t ws_size,
                              hipStream_t stream) {
  const float* query = (const float*)d_in[0];
  const float* Wqkv  = (const float*)d_in[1];
  const float* bqkv  = (const float*)d_in[2];
  const float* Wo    = (const float*)d_in[3];
  // d_in[4] = bo — reference does NOT add it
  const float* fcos  = (const float*)d_in[5];
  const float* fsin  = (const float*)d_in[6];
  float* out = (float*)d_out;
  char* ws = (char*)d_ws;

  // workspace layout (bytes), total 96MB
  u16* WQb = (u16*)(ws + 0);          // 6144x2048 bf16 = 25165824
  u16* WOb = (u16*)(ws + 25165824);   // 2048x2048 bf16 =  8388608
  u16* A1  = (u16*)(ws + 33554432);   // 4096x2048 bf16 (query; reused as attn out)
  u16* QH  = (u16*)(ws + 50331648);   // [32][2048][128] bf16
  u16* KH  = (u16*)(ws + 67108864);
  u16* VT  = (u16*)(ws + 83886080);   // [32][128][2048] bf16  (end: 100663296)

  cvt_bf16<<<4096, 256, 0, stream>>>(query, A1, 1048576);
  cvt_bf16<<<6144, 256, 0, stream>>>(Wqkv, WQb, 1572864);
  cvt_bf16<<<2048, 256, 0, stream>>>(Wo,   WOb,  524288);

  gemmP<1, 24><<<768, 512, 0, stream>>>(A1, WQb, 2048, NE3,
                                        fcos, fsin, bqkv, QH, KH, VT, nullptr);

  attn_fwd<<<1024, 256, 0, stream>>>(QH, KH, VT, A1);

  gemmP<0, 8><<<256, 512, 0, stream>>>(A1, WOb, 2048, EMB,
                                       nullptr, nullptr, nullptr,
                                       nullptr, nullptr, nullptr, out);
}